// Round 2
// baseline (862.778 us; speedup 1.0000x reference)
//
#include <hip/hip_runtime.h>

#define NPTS 262144
#define KVOL 27
#define NPAIRS 65536
#define TP (KVOL*NPAIRS)     // 1769472 total pairs
#define CH 64
#define BROWS 128            // output rows per bucket
#define NB (NPTS/BROWS)      // 2048 buckets
#define NSEG (NB*32)         // segments, k padded to stride 32

typedef __attribute__((ext_vector_type(8))) short bf16x8;
typedef __attribute__((ext_vector_type(4))) float f32x4;

__device__ inline unsigned short f2bf(float x){
  unsigned int u = __float_as_uint(x);
  u += 0x7FFFu + ((u >> 16) & 1u);   // RNE
  return (unsigned short)(u >> 16);
}

__device__ inline bf16x8 pack8(float4 a, float4 b){
  bf16x8 r;
  r[0]=(short)f2bf(a.x); r[1]=(short)f2bf(a.y); r[2]=(short)f2bf(a.z); r[3]=(short)f2bf(a.w);
  r[4]=(short)f2bf(b.x); r[5]=(short)f2bf(b.y); r[6]=(short)f2bf(b.z); r[7]=(short)f2bf(b.w);
  return r;
}

// ---- feat fp32 -> bf16 ----
__global__ void k_conv_feat(const float* __restrict__ f, unsigned short* __restrict__ o){
  int i = blockIdx.x * blockDim.x + threadIdx.x;   // NPTS*CH/4
  float4 v = ((const float4*)f)[i];
  ushort4 r;
  r.x = f2bf(v.x); r.y = f2bf(v.y); r.z = f2bf(v.z); r.w = f2bf(v.w);
  ((ushort4*)o)[i] = r;
}

// ---- weight fp32 [K][Cin][Cout] -> bf16 packed [k][kb][col][j] ----
__global__ void k_pack_w(const float* __restrict__ w, unsigned short* __restrict__ o){
  int i = blockIdx.x * blockDim.x + threadIdx.x;
  if (i >= KVOL*CH*CH) return;
  int j = i & 7, col = (i >> 3) & 63, kb = (i >> 9) & 7, k = i >> 12;
  o[i] = f2bf(w[(k*CH + kb*8 + j)*CH + col]);
}

// ---- pass A: histogram pairs into (bucket,k) segments ----
__global__ void k_count(const int2* __restrict__ km, int* __restrict__ cnt){
  int i = blockIdx.x*256 + threadIdx.x;   // TP threads
  int2 io = km[i];
  int k = i >> 16;                        // NPAIRS = 65536 per k
  atomicAdd(&cnt[((io.y >> 7) << 5) | k], 1);
}

// ---- pass B: exclusive prefix scan of 65536 counters (single block) ----
__global__ void k_scan(const int* __restrict__ cnt, int* __restrict__ off, int* __restrict__ cursor){
  int t = threadIdx.x;                    // 1024 threads
  int base = t*64;
  int loc[64]; int sum = 0;
  #pragma unroll
  for (int i = 0; i < 64; i++){ loc[i] = sum; sum += cnt[base+i]; }
  int l = t & 63;
  int v = sum;
  #pragma unroll
  for (int d = 1; d < 64; d <<= 1){ int u = __shfl_up(v, d, 64); if (l >= d) v += u; }
  __shared__ int wt[16], wbase[16];
  if (l == 63) wt[t>>6] = v;
  __syncthreads();
  if (t == 0){ int a = 0; for (int w = 0; w < 16; w++){ wbase[w] = a; a += wt[w]; } }
  __syncthreads();
  int tb = wbase[t>>6] + v - sum;         // exclusive base for this thread
  #pragma unroll
  for (int i = 0; i < 64; i++){ int x = tb + loc[i]; off[base+i] = x; cursor[base+i] = x; }
  if (t == 1023) off[NSEG] = tb + sum;
}

// ---- pass C: scatter packed records (in:18b | outlo:7b) ----
__global__ void k_scatter(const int2* __restrict__ km, int* __restrict__ cursor,
                          int* __restrict__ records){
  int i = blockIdx.x*256 + threadIdx.x;
  int2 io = km[i];
  int k = i >> 16;
  int pos = atomicAdd(&cursor[((io.y >> 7) << 5) | k], 1);
  records[pos] = io.x | ((io.y & 127) << 18);
}

// ---- pass D: bucketed conv. One block per bucket, LDS accumulator, fused stats ----
template<bool BF16G>
__global__ __launch_bounds__(256, 4) void k_conv2(
    const unsigned short* __restrict__ featb, const float* __restrict__ featf,
    const unsigned short* __restrict__ wpack, const int* __restrict__ records,
    const int* __restrict__ off, float* __restrict__ out, float* __restrict__ stats)
{
  extern __shared__ float sm[];
  float* acc_s = sm;              // BROWS*CH = 8192 floats
  float* red   = sm + BROWS*CH;   // 256 floats
  int b = blockIdx.x;
  int tid = threadIdx.x;
  int wv = tid>>6, l = tid&63, lg = l>>4, li = l&15;

  for (int i = tid; i < BROWS*CH/4; i += 256) ((float4*)acc_s)[i] = make_float4(0,0,0,0);
  __syncthreads();

  const bf16x8* wp = (const bf16x8*)wpack;
  const bf16x8* fb = (const bf16x8*)featb;
  const float4* ff = (const float4*)featf;

  for (int k = 0; k < KVOL; k++){
    int s = (b << 5) | k;
    int beg = off[s], end = off[s+1];
    int cnt = end - beg;
    if (cnt == 0) continue;
    // B fragments for offset k (wave-uniform, L2-hot)
    bf16x8 B[4][2];
    #pragma unroll
    for (int t = 0; t < 4; t++)
      #pragma unroll
      for (int kk = 0; kk < 2; kk++)
        B[t][kk] = wp[(k*8 + kk*4 + lg)*64 + t*16 + li];
    int ngr = (cnt + 15) >> 4;
    for (int g = wv; g < ngr; g += 4){
      int slot = g*16 + li;
      int rec = (slot < cnt) ? records[beg + slot] : 0;
      int in = rec & 0x3FFFF;
      int outlo = rec >> 18;
      bf16x8 A0, A1;
      if (BF16G){
        A0 = fb[in*8 + lg];
        A1 = fb[in*8 + 4 + lg];
      } else {
        float4 u0 = ff[in*16 + lg*2],     u1 = ff[in*16 + lg*2 + 1];
        float4 u2 = ff[in*16 + 8 + lg*2], u3 = ff[in*16 + 8 + lg*2 + 1];
        A0 = pack8(u0, u1);
        A1 = pack8(u2, u3);
      }
      f32x4 acc[4];
      #pragma unroll
      for (int t = 0; t < 4; t++){
        acc[t] = (f32x4)(0.0f);
        acc[t] = __builtin_amdgcn_mfma_f32_16x16x32_bf16(A0, B[t][0], acc[t], 0, 0, 0);
        acc[t] = __builtin_amdgcn_mfma_f32_16x16x32_bf16(A1, B[t][1], acc[t], 0, 0, 0);
      }
      // D row lg*4+r = pair slot g*16+lg*4+r; cols t*16+li
      int orow[4];
      #pragma unroll
      for (int r = 0; r < 4; r++) orow[r] = __shfl(outlo, lg*4 + r, 64);
      #pragma unroll
      for (int r = 0; r < 4; r++){
        if (g*16 + lg*4 + r < cnt){
          float* basep = acc_s + orow[r]*CH;
          #pragma unroll
          for (int t = 0; t < 4; t++)
            atomicAdd(basep + t*16 + li, acc[t][r]);
        }
      }
    }
  }
  __syncthreads();

  // fused per-channel stats for BN
  int c = tid & 63, rg = tid >> 6;
  float s1 = 0.f, s2 = 0.f;
  for (int row = rg; row < BROWS; row += 4){
    float v = acc_s[row*CH + c];
    s1 += v; s2 += v*v;
  }
  red[tid] = s1; __syncthreads();
  if (tid < 64) s1 = red[tid] + red[tid+64] + red[tid+128] + red[tid+192];
  __syncthreads();
  red[tid] = s2; __syncthreads();
  if (tid < 64){
    s2 = red[tid] + red[tid+64] + red[tid+128] + red[tid+192];
    atomicAdd(&stats[tid], s1);
    atomicAdd(&stats[64 + tid], s2);
  }

  // coalesced non-atomic bucket flush
  float4* ob = (float4*)(out + (size_t)b*BROWS*CH);
  for (int i = tid; i < BROWS*CH/4; i += 256) ob[i] = ((const float4*)acc_s)[i];
}

// ---- BN (batch stats, biased var) + ReLU, in place ----
__global__ void k_bn(float* __restrict__ out, const float* __restrict__ stats,
                     const float* __restrict__ g, const float* __restrict__ b){
  int i = blockIdx.x * blockDim.x + threadIdx.x;  // NPTS*CH/4
  float4 v = ((const float4*)out)[i];
  int c0 = (i * 4) & 63;
  float vals[4] = {v.x, v.y, v.z, v.w};
  float res[4];
  #pragma unroll
  for (int q = 0; q < 4; q++){
    int c = c0 + q;
    float mean = stats[c] * (1.0f/NPTS);
    float var  = stats[64+c] * (1.0f/NPTS) - mean*mean;
    float inv  = rsqrtf(var + 1e-5f);
    float y = (vals[q] - mean) * inv * g[c] + b[c];
    res[q] = fmaxf(y, 0.0f);
  }
  float4 r; r.x=res[0]; r.y=res[1]; r.z=res[2]; r.w=res[3];
  ((float4*)out)[i] = r;
}

extern "C" void kernel_launch(void* const* d_in, const int* in_sizes, int n_in,
                              void* d_out, int out_size, void* d_ws, size_t ws_size,
                              hipStream_t stream) {
  const float* feat   = (const float*)d_in[0];
  const int*   kmap   = (const int*)d_in[3];
  const float* weight = (const float*)d_in[4];
  const float* bnw    = (const float*)d_in[5];
  const float* bnb    = (const float*)d_in[6];
  float* out = (float*)d_out;

  char* ws = (char*)d_ws;
  size_t cur = 0;
  auto take = [&](size_t bytes){
    cur = (cur + 255) & ~(size_t)255;
    size_t p = cur; cur += bytes; return p;
  };
  float* stats          = (float*)(ws + take(2*CH*sizeof(float)));
  int* cnt              = (int*)(ws + take((size_t)NSEG*4));
  int* off              = (int*)(ws + take((size_t)(NSEG+1)*4));
  int* cursor           = (int*)(ws + take((size_t)NSEG*4));
  unsigned short* wpack = (unsigned short*)(ws + take((size_t)KVOL*CH*CH*2));
  int* records          = (int*)(ws + take((size_t)TP*4));
  size_t featb_off      = take((size_t)NPTS*CH*2);
  bool useBf16 = (ws_size >= cur);
  unsigned short* featb = (unsigned short*)(ws + featb_off);

  hipMemsetAsync(cnt, 0, (size_t)NSEG*4, stream);
  hipMemsetAsync(stats, 0, 2*CH*sizeof(float), stream);

  k_pack_w<<<(KVOL*CH*CH + 255)/256, 256, 0, stream>>>(weight, wpack);
  if (useBf16)
    k_conv_feat<<<NPTS*CH/4/256, 256, 0, stream>>>(feat, featb);

  const int2* km = (const int2*)kmap;
  k_count<<<TP/256, 256, 0, stream>>>(km, cnt);
  k_scan<<<1, 1024, 0, stream>>>(cnt, off, cursor);
  k_scatter<<<TP/256, 256, 0, stream>>>(km, cursor, records);

  size_t smem = (size_t)(BROWS*CH + 256) * sizeof(float);
  if (useBf16)
    k_conv2<true><<<NB, 256, smem, stream>>>(featb, feat, wpack, records, off, out, stats);
  else
    k_conv2<false><<<NB, 256, smem, stream>>>(featb, feat, wpack, records, off, out, stats);

  k_bn<<<NPTS*CH/4/256, 256, 0, stream>>>(out, stats, bnw, bnb);
}